// Round 7
// baseline (160.592 us; speedup 1.0000x reference)
//
#include <hip/hip_runtime.h>

// Batched Thomas solve, B=2048 rows, N=8192, fp32. One block per row.
// TB=1024 x CH=8. R7 vs R6:
//  - arrays compressed to 24 floats: va(->gv in place), vf(->hv->dpv->uv in
//    place), cpv. R5 (56 floats) and R6 (40 floats + long live ranges) both
//    spilled to scratch (WRITE_SIZE 144/128 MiB vs 64); R4's clean case was 40
//    floats with short ranges. 24 floats buys the allocator real slack.
//  - the three serial <=15-iter cross-wave prefix loops (dependent ds_read
//    chains) replaced by 16-lane shuffle scans (4 rounds; NWAVE==16).
// Algebra unchanged from R6 (Moebius cp-scan + affine dp/backward scans),
// which passed at absmax 0.0156.

#define NN 8192
#define TB 1024
#define CH 8           // NN / TB
#define NWAVE (TB/64)  // 16

__device__ __forceinline__ float frcp(float x) { return __builtin_amdgcn_rcpf(x); }

__global__ __launch_bounds__(TB, 8)
void thomas_kernel(const float* __restrict__ alpha,
                   const float* __restrict__ fvec,
                   float* __restrict__ out)
{
    __shared__ float wq[NWAVE][4];  // fwd Moebius wave totals (p,q,u,v)
    __shared__ float wd[NWAVE][2];  // dp affine wave totals (G,H)
    __shared__ float wb[NWAVE][2];  // bwd affine wave totals (A,B)

    const int t    = threadIdx.x;
    const int lane = t & 63;
    const int wid  = t >> 6;
    const int l16  = lane & 15;
    const int row  = blockIdx.x;
    const float* __restrict__ arow = alpha + (size_t)row * NN;
    const int base = t * CH;

    // ---- load alpha chunk + halo, f chunk into registers ----
    float va[CH], vf[CH];
    {
        const float4* a4 = reinterpret_cast<const float4*>(arow + base);
        const float4* f4 = reinterpret_cast<const float4*>(fvec + base);
        #pragma unroll
        for (int k = 0; k < CH / 4; ++k) {
            float4 x = a4[k];
            va[4*k+0]=x.x; va[4*k+1]=x.y; va[4*k+2]=x.z; va[4*k+3]=x.w;
            float4 y = f4[k];
            vf[4*k+0]=y.x; vf[4*k+1]=y.y; vf[4*k+2]=y.z; vf[4*k+3]=y.w;
        }
    }
    const float aL = (t > 0)      ? arow[base - 1]  : 0.0f;  // => a_0 = 0
    const float aR = (t < TB - 1) ? arow[base + CH] : 0.0f;  // => c_{N-1} = 0

    // ---- Phase A: compose chunk Moebius map for cp; normalize v -> 1 ----
    // cp_i = c_i/(b_i - a_i cp_{i-1})  <=>  M_i = [[0,c],[-a,b]]
    float p, q, u, v;
    {
        const float ai0 = aL * aL;
        const float bi0 = 1.0f + va[0]*va[0]*va[0];
        const float ci0 = va[1] * (va[1] + 2.0f);
        p = 0.0f; q = ci0; u = -ai0; v = bi0;
    }
    #pragma unroll
    for (int k = 1; k < CH; ++k) {
        const float am1 = va[k-1];
        const float ap1 = (k == CH - 1) ? aR : va[k+1];
        const float ai = am1 * am1;
        const float bi = 1.0f + va[k]*va[k]*va[k];
        const float ci = ap1 * (ap1 + 2.0f);
        const float np = ci*u,        nq = ci*v;
        const float nu = bi*u - ai*p, nv = bi*v - ai*q;
        p = np; q = nq; u = nu; v = nv;
    }
    { const float inv = frcp(v); p*=inv; q*=inv; u*=inv; v = 1.0f; }

    // ---- wave-inclusive Moebius scan (mine o earlier) ----
    #pragma unroll
    for (int off = 1; off < 64; off <<= 1) {
        const float p1 = __shfl_up(p, off);
        const float q1 = __shfl_up(q, off);
        const float u1 = __shfl_up(u, off);
        const float v1 = __shfl_up(v, off);
        if (lane >= off) {
            const float np = p*p1 + q*u1;
            const float nq = p*q1 + q*v1;
            const float nu = u*p1 + v*u1;
            const float nv = u*q1 + v*v1;
            p = np; q = nq; u = nu; v = nv;
        }
    }
    if (lane == 63) { wq[wid][0]=p; wq[wid][1]=q; wq[wid][2]=u; wq[wid][3]=v; }
    __syncthreads();

    // exclusive-within-wave
    float ep=__shfl_up(p,1), eq=__shfl_up(q,1), eu=__shfl_up(u,1), ev=__shfl_up(v,1);
    if (lane == 0) { ep=1.f; eq=0.f; eu=0.f; ev=1.f; }

    // cross-wave prefix via 16-lane shuffle scan (replaces serial loop)
    float cp;
    {
        float xp=wq[l16][0], xq=wq[l16][1], xu=wq[l16][2], xv=wq[l16][3];
        #pragma unroll
        for (int off = 1; off < 16; off <<= 1) {
            const float p1=__shfl_up(xp,off), q1=__shfl_up(xq,off);
            const float u1=__shfl_up(xu,off), v1=__shfl_up(xv,off);
            if (l16 >= off) {
                const float np = xp*p1 + xq*u1;
                const float nq = xp*q1 + xq*v1;
                const float nu = xu*p1 + xv*u1;
                const float nv = xu*q1 + xv*v1;
                xp=np; xq=nq; xu=nu; xv=nv;
            }
        }
        const int src = (wid > 0) ? (wid - 1) : 0;
        const float Pq = __shfl(xq, src);
        const float Pv = __shfl(xv, src);
        const float cpP = (wid > 0) ? Pq * frcp(Pv) : 0.0f;  // wave-incoming cp
        cp = (ep*cpP + eq) * frcp(eu*cpP + ev);              // thread-incoming cp
    }

    // ---- Phase C1: cp replay; stash cpv; build (G,H); va->gv, vf->hv in place ----
    float cpv[CH];
    float g0 = 0.f, G = 1.f, H = 0.f;
    #pragma unroll
    for (int k = 0; k < CH; ++k) {
        const float am1 = (k == 0)      ? aL : va[k-1];
        const float ap1 = (k == CH - 1) ? aR : va[k+1];
        const float ai = am1 * am1;
        const float bi = 1.0f + va[k]*va[k]*va[k];
        const float ci = ap1 * (ap1 + 2.0f);
        const float rd = frcp(bi - ai*cp);
        cp = ci * rd;
        cpv[k] = cp;
        const float gk = ai * rd;
        const float hk = vf[k] * rd;
        H = hk - gk*H;
        G = -gk * G;
        if (k == 0) g0 = gk; else va[k-1] = gk;   // gv stash (am1 already consumed)
        vf[k] = hk;                                // hv stash (f consumed)
    }

    // ---- dp affine wave scan (mine o earlier) ----
    #pragma unroll
    for (int off = 1; off < 64; off <<= 1) {
        const float G1 = __shfl_up(G, off);
        const float H1 = __shfl_up(H, off);
        if (lane >= off) { H = G*H1 + H; G = G*G1; }
    }
    if (lane == 63) { wd[wid][0] = G; wd[wid][1] = H; }
    __syncthreads();

    float eG = __shfl_up(G, 1), eH = __shfl_up(H, 1);
    if (lane == 0) { eG = 1.f; eH = 0.f; }

    float dp;
    {   // cross-wave prefix via 16-lane shuffle scan
        float xg = wd[l16][0], xh = wd[l16][1];
        #pragma unroll
        for (int off = 1; off < 16; off <<= 1) {
            const float g1 = __shfl_up(xg, off);
            const float h1 = __shfl_up(xh, off);
            if (l16 >= off) { xh = xg*h1 + xh; xg = xg*g1; }
        }
        const int src = (wid > 0) ? (wid - 1) : 0;
        float Ph = __shfl(xh, src);
        if (wid == 0) Ph = 0.0f;
        dp = eG*Ph + eH;   // thread-incoming dp
    }

    // ---- Phase C2: dp replay, dpv stored into vf in place ----
    #pragma unroll
    for (int k = 0; k < CH; ++k) {
        const float gk = (k == 0) ? g0 : va[k-1];
        dp = vf[k] - gk*dp;   // vf[k] holds hk; last read
        vf[k] = dp;           // now holds dpv[k]
    }

    // ---- Phase D: backward affine chunk map u_left = A*u_right + B ----
    float A = -cpv[CH-1], Bb = vf[CH-1];
    #pragma unroll
    for (int k = CH - 2; k >= 0; --k) {
        Bb = vf[k] - cpv[k]*Bb;
        A  = -cpv[k]*A;
    }
    // wave-inclusive suffix scan: comp(mine, later)
    #pragma unroll
    for (int off = 1; off < 64; off <<= 1) {
        const float A1 = __shfl_down(A, off);
        const float B1 = __shfl_down(Bb, off);
        if (lane < 64 - off) { Bb = A*B1 + Bb; A = A*A1; }
    }
    if (lane == 0) { wb[wid][0] = A; wb[wid][1] = Bb; }
    __syncthreads();

    float eA = __shfl_down(A, 1), eB = __shfl_down(Bb, 1);
    if (lane == 63) { eA = 1.f; eB = 0.f; }

    float u_in;
    {   // cross-wave suffix via reversed 16-lane shuffle scan
        float ya = wb[15 - l16][0], yb = wb[15 - l16][1];
        #pragma unroll
        for (int off = 1; off < 16; off <<= 1) {
            const float a1 = __shfl_up(ya, off);
            const float b1 = __shfl_up(yb, off);
            if (l16 >= off) { yb = ya*b1 + yb; ya = ya*a1; }
        }
        const int src = (wid <= 14) ? (14 - wid) : 0;
        float SB = __shfl(yb, src);
        if (wid == 15) SB = 0.0f;
        u_in = eA*SB + eB;
    }

    // ---- final back-substitution in place (vf: dpv -> u) + float4 stores ----
    float un = u_in;
    #pragma unroll
    for (int k = CH - 1; k >= 0; --k) {
        un = vf[k] - cpv[k]*un;
        vf[k] = un;
    }
    float4* o4 = reinterpret_cast<float4*>(out + (size_t)row * NN + base);
    #pragma unroll
    for (int k = 0; k < CH / 4; ++k) {
        o4[k] = make_float4(vf[4*k+0], vf[4*k+1], vf[4*k+2], vf[4*k+3]);
    }
}

extern "C" void kernel_launch(void* const* d_in, const int* in_sizes, int n_in,
                              void* d_out, int out_size, void* d_ws, size_t ws_size,
                              hipStream_t stream) {
    const float* alpha = (const float*)d_in[0];
    const float* fvec  = (const float*)d_in[1];
    float* out = (float*)d_out;
    const int nrows = out_size / NN;   // 2048
    thomas_kernel<<<nrows, TB, 0, stream>>>(alpha, fvec, out);
}